// Round 5
// baseline (3776.383 us; speedup 1.0000x reference)
//
#include <hip/hip_runtime.h>
#include <math.h>

// Problem constants
#define T_STEPS 2048
#define H 256
#define NBATCH 64
#define OUT_ELEMS 33554432   // NB*T*H
#define HSZ 16384            // NB*H

// Chunked pre-activation prefetch for the recurrent kernels
#define CH 4
#define NCHUNK (T_STEPS / CH)

// t-segments for the independent-row MV kernel: 64 b x 4 = 256 wgs (1/CU)
#define TSEG 4
#define TROWS (T_STEPS / TSEG)

// LDS h layout: 16 k-slices of 16 floats at pitch 20 (320 floats/buffer).
// Slice bases mod 32 = {0,20,8,28,16,4,24,12,...} -> any wave ds_read_b128
// (16 distinct float4 addrs, 4-lane broadcast) hits each bank at most twice;
// 2-way is free (m136). Proven-zero-conflict predecessor had same property.
#define LROW 320
#define LADDR(f) (((f) >> 4) * 20 + ((f) & 15))

typedef float v2f __attribute__((ext_vector_type(2)));

// Workgroup barrier WITHOUT the vmcnt(0) drain __syncthreads would emit.
// Only LDS ordering is needed across the barrier for the h double-buffer;
// global stores stay in flight (fire-and-forget).
#define BAR() asm volatile("s_waitcnt lgkmcnt(0)\n\ts_barrier" ::: "memory")

// 16-lane butterfly reduce on the VALU via DPP (no LDS-pipe traffic).
// xor1 (quad_perm 1,0,3,2), xor2 (quad_perm 2,3,0,1), xor4 (row_half_mirror),
// xor8-within-16 (row_ror:8). Leaves the 16-lane group sum in all 16 lanes.
__device__ __forceinline__ float red16(float v) {
    v += __int_as_float(__builtin_amdgcn_update_dpp(
            0, __float_as_int(v), 0xB1, 0xF, 0xF, true));
    v += __int_as_float(__builtin_amdgcn_update_dpp(
            0, __float_as_int(v), 0x4E, 0xF, 0xF, true));
    v += __int_as_float(__builtin_amdgcn_update_dpp(
            0, __float_as_int(v), 0x141, 0xF, 0xF, true));
    v += __int_as_float(__builtin_amdgcn_update_dpp(
            0, __float_as_int(v), 0x128, 0xF, 0xF, true));
    return v;
}

// Fast tanh: 1 - 2/(exp(2x)+1). ~2e-7 abs error, exact +/-1 at saturation.
__device__ __forceinline__ float ftanh(float x) {
    float e = __expf(2.0f * x);
    return __builtin_fmaf(-2.0f, __builtin_amdgcn_rcpf(e + 1.0f), 1.0f);
}

// ---------------------------------------------------------------------------
// Phase 1: pre0[b][t][n] = x[b][t][:] @ WI0 + BI0   (written into d_out)
// (proven kernel, unchanged)
// ---------------------------------------------------------------------------
__global__ __launch_bounds__(256) void k_gemm_pre0(
    const float* __restrict__ x, const float* __restrict__ WI,
    const float* __restrict__ BI, float* __restrict__ pre)
{
    __shared__ float As[16][132];   // A stored transposed [k][m], padded
    __shared__ float Bs[16][68];
    const int tid = threadIdx.x;
    const size_t mbase = (size_t)blockIdx.x * 128;
    const int nbase = blockIdx.y * 64;
    const int am = tid >> 1, ak = (tid & 1) * 8;
    const int bk = tid >> 4, bn = (tid & 15) * 4;
    const int ty = tid >> 4, tx = tid & 15;
    const int m0 = ty * 8, n0 = tx * 4;
    float acc[8][4];
    #pragma unroll
    for (int i = 0; i < 8; i++)
        #pragma unroll
        for (int j = 0; j < 4; j++) acc[i][j] = 0.f;

    for (int k0 = 0; k0 < 256; k0 += 16) {
        float4 a0 = *(const float4*)(x + (mbase + am) * 256 + k0 + ak);
        float4 a1 = *(const float4*)(x + (mbase + am) * 256 + k0 + ak + 4);
        float4 bv = *(const float4*)(WI + (size_t)(k0 + bk) * 256 + nbase + bn);
        __syncthreads();
        As[ak + 0][am] = a0.x; As[ak + 1][am] = a0.y;
        As[ak + 2][am] = a0.z; As[ak + 3][am] = a0.w;
        As[ak + 4][am] = a1.x; As[ak + 5][am] = a1.y;
        As[ak + 6][am] = a1.z; As[ak + 7][am] = a1.w;
        *(float4*)&Bs[bk][bn] = bv;
        __syncthreads();
        #pragma unroll
        for (int kk = 0; kk < 16; kk++) {
            float4 av0 = *(const float4*)&As[kk][m0];
            float4 av1 = *(const float4*)&As[kk][m0 + 4];
            float4 bv4 = *(const float4*)&Bs[kk][n0];
            float a[8] = {av0.x, av0.y, av0.z, av0.w, av1.x, av1.y, av1.z, av1.w};
            float b[4] = {bv4.x, bv4.y, bv4.z, bv4.w};
            #pragma unroll
            for (int i = 0; i < 8; i++)
                #pragma unroll
                for (int j = 0; j < 4; j++)
                    acc[i][j] += a[i] * b[j];
        }
    }
    float4 bi = *(const float4*)(BI + nbase + n0);
    #pragma unroll
    for (int i = 0; i < 8; i++) {
        float4 r;
        r.x = acc[i][0] + bi.x; r.y = acc[i][1] + bi.y;
        r.z = acc[i][2] + bi.z; r.w = acc[i][3] + bi.w;
        *(float4*)(pre + (mbase + m0 + i) * 256 + nbase + n0) = r;
    }
}

// Thread map (512 threads): ke = tid&15 (16-float k-slice), jb = tid>>4
// (8 output columns j0 = jb*8). Weights: Wp[c][p] = {W[k0+2p][j0+c],
// W[k0+2p+1][j0+c]}, 64 v2f = 128 VGPRs. 64 pk-FMA + 8 collapse + 32 DPP
// reduce per lane per step. Per CU per step: 32 ds_read_b128 (32 KB).
#define LOAD_WP(WSRC)                                                       \
    v2f Wp[8][8];                                                           \
    {                                                                       \
        const float* wp = (WSRC) + (size_t)k0 * H + j0;                     \
        _Pragma("unroll")                                                   \
        for (int p = 0; p < 8; p++) {                                       \
            const float* r0 = wp + (size_t)(2 * p) * H;                     \
            const float* r1 = r0 + H;                                       \
            float4 a0 = *(const float4*)r0;                                 \
            float4 b0 = *(const float4*)(r0 + 4);                           \
            float4 a1 = *(const float4*)r1;                                 \
            float4 b1 = *(const float4*)(r1 + 4);                           \
            Wp[0][p] = (v2f){a0.x, a1.x}; Wp[1][p] = (v2f){a0.y, a1.y};     \
            Wp[2][p] = (v2f){a0.z, a1.z}; Wp[3][p] = (v2f){a0.w, a1.w};     \
            Wp[4][p] = (v2f){b0.x, b1.x}; Wp[5][p] = (v2f){b0.y, b1.y};     \
            Wp[6][p] = (v2f){b0.z, b1.z}; Wp[7][p] = (v2f){b0.w, b1.w};     \
        }                                                                   \
    }

// MV core: reads this lane's 16-float h slice (4 b128), 64 pk-FMA, reduce.
// Afterwards s0..s3 hold the 4 column sums this lane's writer half owns
// (ke&7==0 lanes: ke>>3 selects low/high 4 of the 8 jb columns).
#define MV_CORE(HBASE)                                                      \
    float s0, s1, s2, s3;                                                   \
    {                                                                       \
        v2f c0 = {0,0}, c1 = {0,0}, c2 = {0,0}, c3 = {0,0};                 \
        v2f c4 = {0,0}, c5 = {0,0}, c6 = {0,0}, c7 = {0,0};                 \
        _Pragma("unroll")                                                   \
        for (int r = 0; r < 4; r++) {                                       \
            float4 h4 = *(const float4*)((HBASE) + 4 * r);                  \
            v2f hA = {h4.x, h4.y}, hB = {h4.z, h4.w};                       \
            c0 = __builtin_elementwise_fma(hA, Wp[0][2*r],   c0);           \
            c1 = __builtin_elementwise_fma(hA, Wp[1][2*r],   c1);           \
            c2 = __builtin_elementwise_fma(hA, Wp[2][2*r],   c2);           \
            c3 = __builtin_elementwise_fma(hA, Wp[3][2*r],   c3);           \
            c4 = __builtin_elementwise_fma(hA, Wp[4][2*r],   c4);           \
            c5 = __builtin_elementwise_fma(hA, Wp[5][2*r],   c5);           \
            c6 = __builtin_elementwise_fma(hA, Wp[6][2*r],   c6);           \
            c7 = __builtin_elementwise_fma(hA, Wp[7][2*r],   c7);           \
            c0 = __builtin_elementwise_fma(hB, Wp[0][2*r+1], c0);           \
            c1 = __builtin_elementwise_fma(hB, Wp[1][2*r+1], c1);           \
            c2 = __builtin_elementwise_fma(hB, Wp[2][2*r+1], c2);           \
            c3 = __builtin_elementwise_fma(hB, Wp[3][2*r+1], c3);           \
            c4 = __builtin_elementwise_fma(hB, Wp[4][2*r+1], c4);           \
            c5 = __builtin_elementwise_fma(hB, Wp[5][2*r+1], c5);           \
            c6 = __builtin_elementwise_fma(hB, Wp[6][2*r+1], c6);           \
            c7 = __builtin_elementwise_fma(hB, Wp[7][2*r+1], c7);           \
        }                                                                   \
        float a0 = red16(c0.x + c0.y), a1 = red16(c1.x + c1.y);             \
        float a2 = red16(c2.x + c2.y), a3 = red16(c3.x + c3.y);             \
        float a4 = red16(c4.x + c4.y), a5 = red16(c5.x + c5.y);             \
        float a6 = red16(c6.x + c6.y), a7 = red16(c7.x + c7.y);             \
        s0 = wsel ? a4 : a0; s1 = wsel ? a5 : a1;                           \
        s2 = wsel ? a6 : a2; s3 = wsel ? a7 : a3;                           \
    }

// ---------------------------------------------------------------------------
// Recurrent layer: one workgroup per batch row, fully private recurrence.
// h state in pitch-20 LDS double buffer; weights in VGPRs; DPP k-reduce;
// tanh/write tail split across 2 writer lanes per 16-group.
// In-place stream: read pre-activation pre_t, write h_t over it (batched).
// ---------------------------------------------------------------------------
__global__ __launch_bounds__(512, 1) void k_rec(
    const float* __restrict__ W,      // [256][256] recurrent weights
    const float* __restrict__ bias_p, // per-column bias row
    const float* __restrict__ hinit,  // [NBATCH][H] initial hidden (layer slice)
    float* buf,                       // stream base (aliased read/write)
    float* hfin)                      // [NBATCH][H] final hidden out
{
    const int b    = blockIdx.x;
    const int tid  = threadIdx.x;
    const int ke   = tid & 15;
    const int jb   = tid >> 4;        // 0..31
    const int j0   = jb * 8;
    const int k0   = ke * 16;
    const int wsel = ke >> 3;
    const bool wr  = (ke & 7) == 0;   // 64 writer lanes, 4 cols each
    const int jc   = j0 + wsel * 4;   // this writer's column group

    __shared__ float hb[2][LROW];

    LOAD_WP(W);

    float4 bias = make_float4(0.f, 0.f, 0.f, 0.f);
    if (wr) bias = *(const float4*)(bias_p + jc);

    if (tid < 64)
        *(float4*)&hb[0][LADDR(tid * 4)] =
            *(const float4*)(hinit + b * H + tid * 4);

    float* st = buf + (size_t)b * T_STEPS * H;

    float4 pc[CH], pn[CH];
    if (wr) {
        #pragma unroll
        for (int s = 0; s < CH; s++)
            pc[s] = *(const float4*)(st + (size_t)s * H + jc);
    }
    __syncthreads();

    for (int n = 0; n < NCHUNK; n++) {
        if (wr && n + 1 < NCHUNK) {          // prefetch next chunk's pre-acts
            #pragma unroll
            for (int s = 0; s < CH; s++)
                pn[s] = *(const float4*)(st + (size_t)((n + 1) * CH + s) * H + jc);
        }
        float4 vout[CH];
        #pragma unroll
        for (int s = 0; s < CH; s++) {
            const int t = n * CH + s;
            const int par = t & 1;
            const float* hbase = &hb[par][20 * ke];
            MV_CORE(hbase);
            if (wr) {
                float v0 = ftanh(s0 + pc[s].x + bias.x);
                float v1 = ftanh(s1 + pc[s].y + bias.y);
                float v2 = ftanh(s2 + pc[s].z + bias.z);
                float v3 = ftanh(s3 + pc[s].w + bias.w);
                *(float4*)&hb[par ^ 1][LADDR(jc)] = make_float4(v0, v1, v2, v3);
                vout[s] = make_float4(v0, v1, v2, v3);
            }
            BAR();   // lgkmcnt only: h visible; global stores stay async
        }
        if (wr) {
            #pragma unroll
            for (int s = 0; s < CH; s++)
                *(float4*)(st + (size_t)(n * CH + s) * H + jc) = vout[s];
            if (n == NCHUNK - 1)
                *(float4*)(hfin + b * H + jc) = vout[CH - 1];
            if (n + 1 < NCHUNK) {
                pc[0] = pn[0]; pc[1] = pn[1]; pc[2] = pn[2]; pc[3] = pn[3];
            }
        }
    }
}

// ---------------------------------------------------------------------------
// Layer-1 input transform: P[b][t][j] = h0[b][t][:] @ WI1 + BI1, in-place.
// Independent rows -> parallel over (b, t-segment); same MV core. 1 wg/CU.
// ---------------------------------------------------------------------------
__global__ __launch_bounds__(512, 1) void k_mv1(
    const float* __restrict__ W2,     // WI layer 1
    const float* __restrict__ bias_p, // BI layer 1
    float* buf)
{
    const int b    = blockIdx.x >> 2; // 64 b x TSEG=4 segments
    const int seg  = blockIdx.x & 3;
    const int tid  = threadIdx.x;
    const int ke   = tid & 15;
    const int jb   = tid >> 4;
    const int j0   = jb * 8;
    const int k0   = ke * 16;
    const int wsel = ke >> 3;
    const bool wr  = (ke & 7) == 0;
    const int jc   = j0 + wsel * 4;

    __shared__ float hb[2][LROW];

    LOAD_WP(W2);

    float4 bias = make_float4(0.f, 0.f, 0.f, 0.f);
    if (wr) bias = *(const float4*)(bias_p + jc);

    float* st = buf + (size_t)b * T_STEPS * H;
    const int t0 = seg * TROWS, tend = t0 + TROWS;

    if (tid < 64)
        *(float4*)&hb[0][LADDR(tid * 4)] =
            *(const float4*)(st + (size_t)t0 * H + tid * 4);
    __syncthreads();

    for (int t = t0; t < tend; t++) {
        const int cur = t & 1;
        const bool ld = (tid < 64) && (t + 1 < tend);
        float4 nx = make_float4(0.f, 0.f, 0.f, 0.f);
        if (ld)                               // prefetch next h0 row
            nx = *(const float4*)(st + (size_t)(t + 1) * H + tid * 4);

        const float* hbase = &hb[cur][20 * ke];
        MV_CORE(hbase);
        if (wr) {
            *(float4*)(st + (size_t)t * H + jc) = make_float4(
                s0 + bias.x, s1 + bias.y, s2 + bias.z, s3 + bias.w);
        }
        if (ld)
            *(float4*)&hb[cur ^ 1][LADDR(tid * 4)] = nx;
        BAR();   // lgkmcnt only: next-row h staged; P stores stay async
    }
}

// ---------------------------------------------------------------------------
extern "C" void kernel_launch(void* const* d_in, const int* in_sizes, int n_in,
                              void* d_out, int out_size, void* d_ws, size_t ws_size,
                              hipStream_t stream)
{
    (void)in_sizes; (void)n_in; (void)out_size; (void)d_ws; (void)ws_size;
    const float* x  = (const float*)d_in[0];
    const float* h0 = (const float*)d_in[1];
    const float* WI = (const float*)d_in[2];
    const float* BI = (const float*)d_in[3];
    const float* WH = (const float*)d_in[4];
    const float* BH = (const float*)d_in[5];
    float* out = (float*)d_out;

    // 1) pre0 = x @ WI0 + BI0                       -> out
    k_gemm_pre0<<<dim3(1024, 4), 256, 0, stream>>>(x, WI, BI, out);
    // 2) layer-0 recurrence, in-place: out <- h0_t stream; h_final[0]
    k_rec<<<64, 512, 0, stream>>>(WH, BH, h0, out, out + OUT_ELEMS);
    // 3) P = h0 @ WI1 + BI1, in-place: out <- P_t stream
    k_mv1<<<NBATCH * TSEG, 512, 0, stream>>>(WI + H * H, BI + H, out);
    // 4) layer-1 recurrence, in-place: out <- h1_t stream; h_final[1]
    k_rec<<<64, 512, 0, stream>>>(WH + H * H, BH + H, h0 + HSZ, out,
                                  out + OUT_ELEMS + HSZ);
}